// Round 1
// baseline (334.693 us; speedup 1.0000x reference)
//
#include <hip/hip_runtime.h>
#include <hip/hip_bf16.h>

#define BATCH 8
#define CDIM  128
#define DK    16
#define NPIX  4096   // 64*64
#define NOUT  160    // 16 q + 16 k + 128 v rows

typedef __attribute__((ext_vector_type(4))) float f32x4;
typedef __attribute__((ext_vector_type(8))) short s16x8;

__device__ __forceinline__ short f2bf(float f) {
    union { float fv; unsigned u; } un; un.fv = f;
    unsigned r = un.u + 0x7FFFu + ((un.u >> 16) & 1u);   // round-to-nearest-even
    return (short)(r >> 16);
}

// ---------------------------------------------------------------------------
// Kernel 1: QKV projection (1x1 conv).  C[160 x 64px] = W[160x128] * X[128x64]
// per block, fp32 math, bf16 outputs to workspace.
// Weights staged fp32 in LDS (broadcast reads), x tile staged fp32 (padded).
// ---------------------------------------------------------------------------
__global__ __launch_bounds__(256) void qkv_proj(
    const float* __restrict__ x,
    const float* __restrict__ wq, const float* __restrict__ bq,
    const float* __restrict__ wk, const float* __restrict__ bk,
    const float* __restrict__ wv, const float* __restrict__ bv,
    short* __restrict__ Qb, short* __restrict__ Kb, short* __restrict__ Vb)
{
    __shared__ __align__(16) float xs[CDIM][68];      // pad 64->68 (16B aligned rows)
    __shared__ __align__(16) float ws[NOUT][128];     // weights, rows: 0..15 q, 16..31 k, 32..159 v

    const int tid   = threadIdx.x;
    const int bid   = blockIdx.x;
    const int b     = bid >> 6;           // 64 pixel-blocks per batch
    const int nbase = (bid & 63) << 6;

    // stage weights (float4, coalesced)
    float4* wsd = (float4*)&ws[0][0];
    for (int i = tid; i < 512;  i += 256) wsd[i]        = ((const float4*)wq)[i];
    for (int i = tid; i < 512;  i += 256) wsd[512 + i]  = ((const float4*)wk)[i];
    for (int i = tid; i < 4096; i += 256) wsd[1024 + i] = ((const float4*)wv)[i];

    // stage x tile [128 c][64 px]
    #pragma unroll
    for (int it = 0; it < 8; ++it) {
        int flat = it * 256 + tid;            // 0..2047
        int c    = flat >> 4;
        int f4   = (flat & 15) << 2;
        float4 v = *(const float4*)(x + ((size_t)(b * CDIM + c) << 12) + nbase + f4);
        *(float4*)&xs[c][f4] = v;
    }
    __syncthreads();

    const int wave  = tid >> 6;
    const int lane  = tid & 63;               // lane = pixel
    const int obase = wave * 40;              // wave owns 40 output rows

    float acc[40];
    #pragma unroll
    for (int i = 0; i < 40; ++i) acc[i] = 0.f;

    for (int c = 0; c < 128; c += 4) {
        float xv0 = xs[c + 0][lane];
        float xv1 = xs[c + 1][lane];
        float xv2 = xs[c + 2][lane];
        float xv3 = xs[c + 3][lane];
        #pragma unroll
        for (int i = 0; i < 40; ++i) {
            const float4 w4 = *(const float4*)&ws[obase + i][c];   // broadcast LDS read
            acc[i] = fmaf(w4.x, xv0, acc[i]);
            acc[i] = fmaf(w4.y, xv1, acc[i]);
            acc[i] = fmaf(w4.z, xv2, acc[i]);
            acc[i] = fmaf(w4.w, xv3, acc[i]);
        }
    }

    #pragma unroll
    for (int i = 0; i < 40; ++i) {
        int o = obase + i;                    // wave-uniform
        float bias; short* dst;
        if (o < 16)      { bias = bq[o];      dst = Qb + ((size_t)(b * DK   + o)        << 12); }
        else if (o < 32) { bias = bk[o - 16]; dst = Kb + ((size_t)(b * DK   + (o - 16)) << 12); }
        else             { bias = bv[o - 32]; dst = Vb + ((size_t)(b * CDIM + (o - 32)) << 12); }
        dst[nbase + lane] = f2bf(acc[i] + bias);
    }
}

// ---------------------------------------------------------------------------
// Kernel 2: flash attention + residual.
// Block = 4 waves x 16 queries = 64 queries; loop over 64 key tiles of 64.
// MFMA 16x16x32 bf16:  A row=lane&15, k=(lane>>4)*8+i ; B col=lane&15, same k;
//                      C/D col=lane&15, row=(lane>>4)*4+reg   (guide §3, m89)
// ---------------------------------------------------------------------------
__global__ __launch_bounds__(256) void attn_fwd(
    const short* __restrict__ Qb, const short* __restrict__ Kb,
    const short* __restrict__ Vb,
    const float* __restrict__ x, float* __restrict__ out)
{
    __shared__ short kT[64][16];                        // K tile transposed [j][d]
    __shared__ __align__(16) short vs[CDIM][72];        // V tile [c][j], pad 64->72
    __shared__ __align__(16) short ps[4][16][72];       // per-wave P [q][j], pad

    const int tid   = threadIdx.x;
    const int bid   = blockIdx.x;
    const int b     = bid & 7;            // batch = bid%8 -> per-XCD L2 locality for K/V
    const int qb    = bid >> 3;
    const int qbase = qb << 6;
    const int wave  = tid >> 6;
    const int lane  = tid & 63;
    const int lo    = lane & 15;
    const int hi    = lane >> 4;

    // Q A-fragment: row(query)=lo, k(d)=hi*8+i ; d>=16 lanes supply zeros
    s16x8 qA;
    #pragma unroll
    for (int i = 0; i < 8; ++i) qA[i] = 0;
    if (hi < 2) {
        const int qcol = qbase + wave * 16 + lo;
        #pragma unroll
        for (int i = 0; i < 8; ++i) {
            int d = hi * 8 + i;
            qA[i] = Qb[((size_t)(b * DK + d) << 12) + qcol];
        }
    }

    f32x4 O[8];
    #pragma unroll
    for (int cf = 0; cf < 8; ++cf) {
        O[cf][0] = 0.f; O[cf][1] = 0.f; O[cf][2] = 0.f; O[cf][3] = 0.f;
    }
    float m_run[4] = {-1e38f, -1e38f, -1e38f, -1e38f};
    float l_run[4] = {0.f, 0.f, 0.f, 0.f};

    f32x4 zero4; zero4[0] = 0.f; zero4[1] = 0.f; zero4[2] = 0.f; zero4[3] = 0.f;

    for (int jt = 0; jt < 64; ++jt) {
        const int jbase = jt << 6;
        __syncthreads();   // prior tile's PV reads complete before overwrite

        // stage K tile: kT[j][d] <- K[d][jbase+j]   (coalesced along j)
        #pragma unroll
        for (int it = 0; it < 4; ++it) {
            int idx = it * 256 + tid;
            int j = idx & 63, d = idx >> 6;
            kT[j][d] = Kb[((size_t)(b * DK + d) << 12) + jbase + j];
        }
        // stage V tile: vs[c][j]  (16B vector loads/stores)
        #pragma unroll
        for (int it = 0; it < 4; ++it) {
            int flat = it * 256 + tid;
            int c  = flat >> 3;
            int j8 = (flat & 7) << 3;
            *(s16x8*)&vs[c][j8] =
                *(const s16x8*)(Vb + ((size_t)(b * CDIM + c) << 12) + jbase + j8);
        }
        __syncthreads();

        // ---- S = Q^T K for this wave's 16 queries x 64 keys
        f32x4 sfr[4];
        #pragma unroll
        for (int jf = 0; jf < 4; ++jf) {
            s16x8 kB;
            #pragma unroll
            for (int i = 0; i < 8; ++i) kB[i] = 0;
            if (hi < 2) kB = *(const s16x8*)&kT[jf * 16 + lo][hi * 8];
            sfr[jf] = __builtin_amdgcn_mfma_f32_16x16x32_bf16(qA, kB, zero4, 0, 0, 0);
        }

        // ---- online softmax (per reg = per query row; reduce over 16 lanes = keys)
        #pragma unroll
        for (int reg = 0; reg < 4; ++reg) {
            float s0 = sfr[0][reg] * 0.25f, s1 = sfr[1][reg] * 0.25f;
            float s2 = sfr[2][reg] * 0.25f, s3 = sfr[3][reg] * 0.25f;
            float mx = fmaxf(fmaxf(s0, s1), fmaxf(s2, s3));
            mx = fmaxf(mx, __shfl_xor(mx, 1));
            mx = fmaxf(mx, __shfl_xor(mx, 2));
            mx = fmaxf(mx, __shfl_xor(mx, 4));
            mx = fmaxf(mx, __shfl_xor(mx, 8));
            float mnew  = fmaxf(m_run[reg], mx);
            float scale = __expf(m_run[reg] - mnew);
            float p0 = __expf(s0 - mnew), p1 = __expf(s1 - mnew);
            float p2 = __expf(s2 - mnew), p3 = __expf(s3 - mnew);
            int q = hi * 4 + reg;              // D-layout row -> query within wave strip
            ps[wave][q][lo]      = f2bf(p0);
            ps[wave][q][16 + lo] = f2bf(p1);
            ps[wave][q][32 + lo] = f2bf(p2);
            ps[wave][q][48 + lo] = f2bf(p3);
            float psum = p0 + p1 + p2 + p3;
            psum += __shfl_xor(psum, 1);
            psum += __shfl_xor(psum, 2);
            psum += __shfl_xor(psum, 4);
            psum += __shfl_xor(psum, 8);
            l_run[reg] = l_run[reg] * scale + psum;
            m_run[reg] = mnew;
            #pragma unroll
            for (int cf = 0; cf < 8; ++cf) O[cf][reg] *= scale;
        }

        // ---- O += P * V^T  (same-wave LDS dep on ps; compiler inserts lgkmcnt)
        s16x8 pA0 = *(const s16x8*)&ps[wave][lo][hi * 8];
        s16x8 pA1 = *(const s16x8*)&ps[wave][lo][32 + hi * 8];
        #pragma unroll
        for (int cf = 0; cf < 8; ++cf) {
            s16x8 vB0 = *(const s16x8*)&vs[cf * 16 + lo][hi * 8];
            s16x8 vB1 = *(const s16x8*)&vs[cf * 16 + lo][32 + hi * 8];
            O[cf] = __builtin_amdgcn_mfma_f32_16x16x32_bf16(pA0, vB0, O[cf], 0, 0, 0);
            O[cf] = __builtin_amdgcn_mfma_f32_16x16x32_bf16(pA1, vB1, O[cf], 0, 0, 0);
        }
    }

    // ---- epilogue: normalize, residual add, coalesced float4 stores along n
    const int q4 = qbase + wave * 16 + hi * 4;        // regs 0..3 are consecutive queries
    float inv0 = 1.f / l_run[0], inv1 = 1.f / l_run[1];
    float inv2 = 1.f / l_run[2], inv3 = 1.f / l_run[3];
    #pragma unroll
    for (int cf = 0; cf < 8; ++cf) {
        int c = cf * 16 + lo;
        size_t base = ((size_t)(b * CDIM + c) << 12) + q4;
        float4 xv = *(const float4*)(x + base);
        float4 ov;
        ov.x = O[cf][0] * inv0 + xv.x;
        ov.y = O[cf][1] * inv1 + xv.y;
        ov.z = O[cf][2] * inv2 + xv.z;
        ov.w = O[cf][3] * inv3 + xv.w;
        *(float4*)(out + base) = ov;
    }
}

// ---------------------------------------------------------------------------
extern "C" void kernel_launch(void* const* d_in, const int* in_sizes, int n_in,
                              void* d_out, int out_size, void* d_ws, size_t ws_size,
                              hipStream_t stream) {
    const float* x  = (const float*)d_in[0];
    const float* wq = (const float*)d_in[1];
    const float* bq = (const float*)d_in[2];
    const float* wk = (const float*)d_in[3];
    const float* bk = (const float*)d_in[4];
    const float* wv = (const float*)d_in[5];
    const float* bv = (const float*)d_in[6];
    float* out = (float*)d_out;

    // workspace: Q,K bf16 [8][16][4096]; V bf16 [8][128][4096]  => 10 MB
    short* Qw = (short*)d_ws;
    short* Kw = Qw + (size_t)BATCH * DK * NPIX;
    short* Vw = Kw + (size_t)BATCH * DK * NPIX;

    qkv_proj<<<dim3(512), dim3(256), 0, stream>>>(x, wq, bq, wk, bk, wv, bv, Qw, Kw, Vw);
    attn_fwd<<<dim3(512), dim3(256), 0, stream>>>(Qw, Kw, Vw, x, out);
}